// Round 1
// baseline (1477.250 us; speedup 1.0000x reference)
//
#include <hip/hip_runtime.h>
#include <stdint.h>

// Problem constants (B, T, V, E, U)
constexpr int NB = 1024;
constexpr int NT = 80;
constexpr int NV = 50000;
constexpr int NE = 512;
constexpr int NU = 512;

typedef __attribute__((ext_vector_type(8))) __bf16 bf16x8;
typedef __attribute__((ext_vector_type(4))) float f32x4;
typedef __attribute__((ext_vector_type(4))) uint16_t u16x4;
typedef __attribute__((ext_vector_type(4))) float float4v;

__device__ __forceinline__ uint16_t f2bf(float f) {
  uint32_t u = __builtin_bit_cast(uint32_t, f);
  u += 0x7FFFu + ((u >> 16) & 1u);   // round-to-nearest-even
  return (uint16_t)(u >> 16);
}
__device__ __forceinline__ float bf2f(uint16_t h) {
  uint32_t u = ((uint32_t)h) << 16;
  return __builtin_bit_cast(float, u);
}
// tanh via exp2-path; stable at +-inf: e->inf gives 1, e->0 gives -1
__device__ __forceinline__ float tanh_fast(float x) {
  float e = __expf(2.0f * x);
  return 1.0f - 2.0f / (e + 1.0f);
}

// ---------------- prep kernels ----------------

// fp32 -> bf16 conversion of the embedding table (float4 in, 4x bf16 out)
__global__ __launch_bounds__(256) void emb_to_bf16(const float* __restrict__ in,
                                                   uint16_t* __restrict__ out) {
  int i = blockIdx.x * 256 + threadIdx.x;           // 6,400,000 float4s
  float4v v = ((const float4v*)in)[i];
  u16x4 o;
  o.x = f2bf(v.x); o.y = f2bf(v.y); o.z = f2bf(v.z); o.w = f2bf(v.w);
  ((u16x4*)out)[i] = o;
}

// Pack a [K=512][N=512] fp32 weight into MFMA-B-fragment order:
// pack[nt][ks][lane][j] = bf16( W[ks*32 + (lane>>4)*8 + j][nt*16 + (lane&15)] )
// so a wave's B-fragment load for (nt, ks) is one coalesced 16B/lane read.
__global__ __launch_bounds__(256) void pack_w(const float* __restrict__ w,
                                              uint16_t* __restrict__ out) {
  int idx = blockIdx.x * 256 + threadIdx.x;  // 0..32767 = 32 nt * 16 ks * 64 lanes
  int lane = idx & 63;
  int ks = (idx >> 6) & 15;
  int nt = idx >> 10;
  int n  = nt * 16 + (lane & 15);
  int k0 = ks * 32 + (lane >> 4) * 8;
  uint16_t v[8];
#pragma unroll
  for (int j = 0; j < 8; j++) v[j] = f2bf(w[(size_t)(k0 + j) * NU + n]);
  u16x4* o = (u16x4*)(out + (size_t)idx * 8);
  o[0] = (u16x4){v[0], v[1], v[2], v[3]};
  o[1] = (u16x4){v[4], v[5], v[6], v[7]};
}

// zero h0 buffer and sync counters (ws is poisoned 0xAA before every launch)
__global__ __launch_bounds__(256) void init_ws(uint16_t* __restrict__ hbuf,
                                               int* __restrict__ cnt) {
  int i = blockIdx.x * 256 + threadIdx.x;           // 131072 threads
  ((u16x4*)hbuf)[i] = (u16x4){0, 0, 0, 0};
  if (i < 2048) cnt[i] = 0;
}

// ---------------- projection GEMM ----------------
// xk[t][b][u] = bf16( emb[tokens[b][t]] @ kernel + bias )
// Block: 64 rows (m) x 512 cols. 4 waves, wave w covers cols w*128..+127.
// A-frags gathered directly from bf16 emb table; B-frags from packed kernel.
__global__ __launch_bounds__(256) void proj_gemm(const int* __restrict__ tokens,
                                                 const uint16_t* __restrict__ embb,
                                                 const uint16_t* __restrict__ kpack,
                                                 const float* __restrict__ bias,
                                                 uint16_t* __restrict__ xk) {
  int wave = threadIdx.x >> 6;
  int lane = threadIdx.x & 63;
  int ln15 = lane & 15;
  int quad = lane >> 4;
  int m0 = blockIdx.x * 64;
  int col0 = wave * 128;

  int tok[4];
#pragma unroll
  for (int mt = 0; mt < 4; mt++) tok[mt] = tokens[m0 + mt * 16 + ln15];

  float bv[8];
#pragma unroll
  for (int nt = 0; nt < 8; nt++) bv[nt] = bias[col0 + nt * 16 + ln15];

  f32x4 acc[4][8];
#pragma unroll
  for (int mt = 0; mt < 4; mt++)
#pragma unroll
    for (int nt = 0; nt < 8; nt++) acc[mt][nt] = (f32x4){0.f, 0.f, 0.f, 0.f};

#pragma unroll 1
  for (int ks = 0; ks < 16; ks++) {
    bf16x8 afr[4];
#pragma unroll
    for (int mt = 0; mt < 4; mt++)
      afr[mt] = *(const bf16x8*)(embb + (size_t)tok[mt] * NE + ks * 32 + quad * 8);
#pragma unroll
    for (int nt = 0; nt < 8; nt++) {
      int ntg = wave * 8 + nt;  // global n-tile 0..31
      bf16x8 bfr = *(const bf16x8*)(kpack + (((size_t)ntg * 16 + ks) * 64 + lane) * 8);
#pragma unroll
      for (int mt = 0; mt < 4; mt++)
        acc[mt][nt] = __builtin_amdgcn_mfma_f32_16x16x32_bf16(afr[mt], bfr, acc[mt][nt], 0, 0, 0);
    }
  }

  // epilogue: C/D layout col = lane&15, row = quad*4 + r. Store to [T][B][U].
#pragma unroll
  for (int mt = 0; mt < 4; mt++) {
#pragma unroll
    for (int r = 0; r < 4; r++) {
      int gm = m0 + mt * 16 + quad * 4 + r;  // flat (b, t) row: gm = b*NT + t
      int t = gm % NT;
      int b = gm / NT;
      size_t obase = ((size_t)t * NB + b) * NU;
#pragma unroll
      for (int nt = 0; nt < 8; nt++) {
        float v = acc[mt][nt][r] + bv[nt];
        xk[obase + col0 + nt * 16 + ln15] = f2bf(v);
      }
    }
  }
}

// ---------------- recurrence ----------------
// 256 blocks: group g = bid&63 owns rows g*16..+15; slice s = bid>>6 owns cols
// s*128..+127. Group blocks {g, g+64, g+128, g+192} map to the same XCD.
// R-slice lives in registers (B-frags) for all 80 steps; h exchanged through
// a double-buffered global bf16 buffer with a per-group counter sync.
__global__ __launch_bounds__(256) void rnn_rec(const uint16_t* __restrict__ xk,
                                               const uint16_t* __restrict__ rpack,
                                               const float* __restrict__ fcw,
                                               const float* __restrict__ fcb,
                                               uint16_t* __restrict__ hbuf,
                                               int* __restrict__ cnt,
                                               float* __restrict__ out) {
  int bid = blockIdx.x;
  int s = bid >> 6;       // slice 0..3
  int g = bid & 63;       // group 0..63
  int wave = threadIdx.x >> 6;
  int lane = threadIdx.x & 63;
  int ln15 = lane & 15;
  int quad = lane >> 4;
  int b0 = g * 16;
  int nt0 = s * 8 + wave * 2;  // this wave's 2 global n-tiles
  int n0 = nt0 * 16;

  // preload R-slice B-fragments: 2 n-tiles x 16 k-steps = 128 VGPR/lane
  bf16x8 bf[2][16];
#pragma unroll
  for (int i = 0; i < 2; i++)
#pragma unroll
    for (int ks = 0; ks < 16; ks++)
      bf[i][ks] = *(const bf16x8*)(rpack + (((size_t)(nt0 + i) * 16 + ks) * 64 + lane) * 8);

  int* mycnt = cnt + g * 32;  // 128B padding between group counters

  for (int t = 0; t < NT; t++) {
    const uint16_t* hcur = hbuf + (size_t)(t & 1) * (NB * NU);
    uint16_t* hnext = hbuf + (size_t)((t + 1) & 1) * (NB * NU);

    f32x4 acc0 = (f32x4){0.f, 0.f, 0.f, 0.f};
    f32x4 acc1 = (f32x4){0.f, 0.f, 0.f, 0.f};
#pragma unroll
    for (int ks = 0; ks < 16; ks++) {
      bf16x8 a = *(const bf16x8*)(hcur + (size_t)(b0 + ln15) * NU + ks * 32 + quad * 8);
      acc0 = __builtin_amdgcn_mfma_f32_16x16x32_bf16(a, bf[0][ks], acc0, 0, 0, 0);
      acc1 = __builtin_amdgcn_mfma_f32_16x16x32_bf16(a, bf[1][ks], acc1, 0, 0, 0);
    }

    const uint16_t* xt = xk + (size_t)t * (NB * NU);
#pragma unroll
    for (int r = 0; r < 4; r++) {
      int row = b0 + quad * 4 + r;
      float x0 = bf2f(xt[(size_t)row * NU + n0 + ln15]);
      float x1 = bf2f(xt[(size_t)row * NU + n0 + 16 + ln15]);
      float h0 = tanh_fast(acc0[r] + x0);
      float h1 = tanh_fast(acc1[r] + x1);
      hnext[(size_t)row * NU + n0 + ln15] = f2bf(h0);
      hnext[(size_t)row * NU + n0 + 16 + ln15] = f2bf(h1);
    }

    // group sync: 4 blocks of this group
    __syncthreads();
    if (threadIdx.x == 0) {
      __threadfence();  // make my h writes visible (agent scope)
      __hip_atomic_fetch_add(mycnt, 1, __ATOMIC_RELAXED, __HIP_MEMORY_SCOPE_AGENT);
      int target = 4 * (t + 1);
      int spin = 0;
      while (__hip_atomic_load(mycnt, __ATOMIC_RELAXED, __HIP_MEMORY_SCOPE_AGENT) < target &&
             spin < (1 << 18))
        spin++;
      __threadfence();  // acquire other slices' h writes
    }
    __syncthreads();
  }

  // final FC + sigmoid: slice 0 of each group handles its 16 rows
  if (s == 0) {
    const uint16_t* hf = hbuf + (size_t)(NT & 1) * (NB * NU);  // NT=80 even -> buf 0
#pragma unroll
    for (int rr = 0; rr < 4; rr++) {
      int row = b0 + wave * 4 + rr;
      const uint16_t* hr = hf + (size_t)row * NU + lane * 8;
      float p = 0.f;
#pragma unroll
      for (int j = 0; j < 8; j++) p += bf2f(hr[j]) * fcw[lane * 8 + j];
#pragma unroll
      for (int off = 32; off; off >>= 1) p += __shfl_down(p, off);
      if (lane == 0) {
        float logit = p + fcb[0];
        out[row] = 1.0f / (1.0f + __expf(-logit));
      }
    }
  }
}

// ---------------- launcher ----------------
extern "C" void kernel_launch(void* const* d_in, const int* in_sizes, int n_in,
                              void* d_out, int out_size, void* d_ws, size_t ws_size,
                              hipStream_t stream) {
  const int* tokens   = (const int*)d_in[0];
  const float* emb    = (const float*)d_in[1];
  const float* kernel_w = (const float*)d_in[2];
  const float* rec_w  = (const float*)d_in[3];
  const float* bias   = (const float*)d_in[4];
  const float* fcw    = (const float*)d_in[5];
  const float* fcb    = (const float*)d_in[6];
  float* out = (float*)d_out;

  // workspace layout (bytes): emb_bf16 51.2MB | kpack 0.5MB | rpack 0.5MB |
  // xk 83.9MB | hbuf 2MB | cnt 8KB  -> ~138.2 MB total
  uint16_t* embb  = (uint16_t*)d_ws;
  uint16_t* kpack = embb + (size_t)NV * NE;            // 25,600,000 shorts
  uint16_t* rpack = kpack + (size_t)NE * NU;           // 262,144 shorts
  uint16_t* xkbuf = rpack + (size_t)NU * NU;           // 262,144 shorts
  uint16_t* hbuf  = xkbuf + (size_t)NT * NB * NU;      // 41,943,040 shorts
  int* cnt        = (int*)(hbuf + (size_t)2 * NB * NU);

  hipLaunchKernelGGL(emb_to_bf16, dim3(25000), dim3(256), 0, stream, emb, embb);
  hipLaunchKernelGGL(pack_w, dim3(128), dim3(256), 0, stream, kernel_w, kpack);
  hipLaunchKernelGGL(pack_w, dim3(128), dim3(256), 0, stream, rec_w, rpack);
  hipLaunchKernelGGL(init_ws, dim3(512), dim3(256), 0, stream, hbuf, cnt);
  hipLaunchKernelGGL(proj_gemm, dim3(1280), dim3(256), 0, stream, tokens, embb, kpack, bias, xkbuf);
  hipLaunchKernelGGL(rnn_rec, dim3(256), dim3(256), 0, stream, xkbuf, rpack, fcw, fcb, hbuf, cnt, out);
}

// Round 2
// 665.804 us; speedup vs baseline: 2.2187x; 2.2187x over previous
//
#include <hip/hip_runtime.h>
#include <stdint.h>

// Problem constants (B, T, V, E, U)
constexpr int NB = 1024;
constexpr int NT = 80;
constexpr int NV = 50000;
constexpr int NE = 512;
constexpr int NU = 512;

typedef __attribute__((ext_vector_type(8))) __bf16 bf16x8;
typedef __attribute__((ext_vector_type(4))) float f32x4;
typedef __attribute__((ext_vector_type(4))) uint16_t u16x4;
typedef __attribute__((ext_vector_type(4))) float float4v;
typedef __attribute__((ext_vector_type(4))) uint32_t u32x4;

__device__ __forceinline__ uint16_t f2bf(float f) {
  uint32_t u = __builtin_bit_cast(uint32_t, f);
  u += 0x7FFFu + ((u >> 16) & 1u);   // round-to-nearest-even
  return (uint16_t)(u >> 16);
}
__device__ __forceinline__ float bf2f(uint16_t h) {
  uint32_t u = ((uint32_t)h) << 16;
  return __builtin_bit_cast(float, u);
}
__device__ __forceinline__ float tanh_fast(float x) {
  float e = __expf(2.0f * x);
  return 1.0f - 2.0f / (e + 1.0f);
}

// ---------------- prep kernels ----------------

// fp32 -> bf16 conversion of the embedding table
__global__ __launch_bounds__(256) void emb_to_bf16(const float* __restrict__ in,
                                                   uint16_t* __restrict__ out) {
  int i = blockIdx.x * 256 + threadIdx.x;           // 6,400,000 float4s
  float4v v = ((const float4v*)in)[i];
  u16x4 o;
  o.x = f2bf(v.x); o.y = f2bf(v.y); o.z = f2bf(v.z); o.w = f2bf(v.w);
  ((u16x4*)out)[i] = o;
}

// Pack a [K=512][N=512] fp32 weight into MFMA-B-fragment order:
// pack[nt][ks][lane][j] = bf16( W[ks*32 + (lane>>4)*8 + j][nt*16 + (lane&15)] )
__global__ __launch_bounds__(256) void pack_w(const float* __restrict__ w,
                                              uint16_t* __restrict__ out) {
  int idx = blockIdx.x * 256 + threadIdx.x;  // 0..32767 = 32 nt * 16 ks * 64 lanes
  int lane = idx & 63;
  int ks = (idx >> 6) & 15;
  int nt = idx >> 10;
  int n  = nt * 16 + (lane & 15);
  int k0 = ks * 32 + (lane >> 4) * 8;
  uint16_t v[8];
#pragma unroll
  for (int j = 0; j < 8; j++) v[j] = f2bf(w[(size_t)(k0 + j) * NU + n]);
  u16x4* o = (u16x4*)(out + (size_t)idx * 8);
  o[0] = (u16x4){v[0], v[1], v[2], v[3]};
  o[1] = (u16x4){v[4], v[5], v[6], v[7]};
}

// ---------------- projection GEMM ----------------
// Row order is t-major: flat row gm = t*NB + b. Block covers 64 rows (one t,
// 64 consecutive b). Output stored as xkp tiles in MFMA C-fragment order:
// tile(t, g=b>>4, ntg) is 256 u16; element (row_in_tile=quad*4+r, col=ln15)
// at [lane*4 + r] with lane = quad*16 + ln15. One dwordx2 store per (mt,nt).
__global__ __launch_bounds__(256) void proj_gemm(const int* __restrict__ tokens,
                                                 const uint16_t* __restrict__ embb,
                                                 const uint16_t* __restrict__ kpack,
                                                 const float* __restrict__ bias,
                                                 uint16_t* __restrict__ xkp) {
  int wave = threadIdx.x >> 6;
  int lane = threadIdx.x & 63;
  int ln15 = lane & 15;
  int quad = lane >> 4;
  int m0 = blockIdx.x * 64;      // flat row base; t fixed per block
  int t = m0 >> 10;
  int b0 = m0 & 1023;
  int col0 = wave * 128;

  int tok[4];
#pragma unroll
  for (int mt = 0; mt < 4; mt++)
    tok[mt] = tokens[(size_t)(b0 + mt * 16 + ln15) * NT + t];

  float bv[8];
#pragma unroll
  for (int nt = 0; nt < 8; nt++) bv[nt] = bias[col0 + nt * 16 + ln15];

  f32x4 acc[4][8];
#pragma unroll
  for (int mt = 0; mt < 4; mt++)
#pragma unroll
    for (int nt = 0; nt < 8; nt++) acc[mt][nt] = (f32x4){0.f, 0.f, 0.f, 0.f};

#pragma unroll 1
  for (int ks = 0; ks < 16; ks++) {
    bf16x8 afr[4];
#pragma unroll
    for (int mt = 0; mt < 4; mt++)
      afr[mt] = *(const bf16x8*)(embb + (size_t)tok[mt] * NE + ks * 32 + quad * 8);
#pragma unroll
    for (int nt = 0; nt < 8; nt++) {
      int ntg = wave * 8 + nt;
      bf16x8 bfr = *(const bf16x8*)(kpack + (((size_t)ntg * 16 + ks) * 64 + lane) * 8);
#pragma unroll
      for (int mt = 0; mt < 4; mt++)
        acc[mt][nt] = __builtin_amdgcn_mfma_f32_16x16x32_bf16(afr[mt], bfr, acc[mt][nt], 0, 0, 0);
    }
  }

  // epilogue: store each 16x16 tile in C-fragment order, coalesced 8B/lane
#pragma unroll
  for (int mt = 0; mt < 4; mt++) {
    int g = (b0 >> 4) + mt;
#pragma unroll
    for (int nt = 0; nt < 8; nt++) {
      int ntg = wave * 8 + nt;
      size_t tile = ((size_t)t * 64 + g) * 32 + ntg;
      u16x4 o;
      o.x = f2bf(acc[mt][nt][0] + bv[nt]);
      o.y = f2bf(acc[mt][nt][1] + bv[nt]);
      o.z = f2bf(acc[mt][nt][2] + bv[nt]);
      o.w = f2bf(acc[mt][nt][3] + bv[nt]);
      *(u16x4*)(xkp + tile * 256 + (size_t)lane * 4) = o;
    }
  }
}

// ---------------- recurrence ----------------
// 64 blocks x 512 threads (8 waves). Block g owns batch rows g*16..+15 and
// computes ALL 512 h-columns -> h lives in LDS, sync is __syncthreads only.
// Wave w owns n-tiles w*4..w*4+3 (cols w*64..+63).
// R tiering per wave (64 frags of 16B/lane): ks 0..11 in VGPRs (192 regs),
// ks 12 in LDS (32 KB), ks 13..15 streamed from L2 each step.
// h stored in LDS in A-fragment chunk order [k/8][row][8] -> conflict-free
// ds_read_b128 A-loads.
__global__ __launch_bounds__(512, 2) void rnn_rec(const uint16_t* __restrict__ xkp,
                                                  const uint16_t* __restrict__ rpack,
                                                  const float* __restrict__ fcw,
                                                  const float* __restrict__ fcb,
                                                  float* __restrict__ out) {
  __shared__ uint16_t hA[64 * 16 * 8];        // 16 KB: [chunk=u/8][row][8]
  __shared__ uint16_t bl[8 * 4 * 64 * 8];     // 32 KB: ks==12 frags [wave][nt][lane][8]

  int g = blockIdx.x;            // 0..63
  int wave = threadIdx.x >> 6;   // 0..7
  int lane = threadIdx.x & 63;
  int ln15 = lane & 15;
  int quad = lane >> 4;
  int nt0 = wave * 4;

  // preload register-resident B-frags (ks 0..11)
  bf16x8 bf[4][12];
#pragma unroll
  for (int nt = 0; nt < 4; nt++)
#pragma unroll
    for (int ks = 0; ks < 12; ks++)
      bf[nt][ks] = *(const bf16x8*)(rpack + (((size_t)(nt0 + nt) * 16 + ks) * 64 + lane) * 8);

  // ks==12 frags into LDS
#pragma unroll
  for (int nt = 0; nt < 4; nt++)
    *(u32x4*)(bl + (((size_t)wave * 4 + nt) * 64 + lane) * 8) =
        *(const u32x4*)(rpack + (((size_t)(nt0 + nt) * 16 + 12) * 64 + lane) * 8);

  // zero h0 (16 KB = 1024 uint4; 512 threads x 2)
  {
    u32x4 z = (u32x4){0u, 0u, 0u, 0u};
    ((u32x4*)hA)[threadIdx.x * 2] = z;
    ((u32x4*)hA)[threadIdx.x * 2 + 1] = z;
  }
  __syncthreads();

  f32x4 acc0, acc1, acc2, acc3;

  for (int t = 0; t < NT; t++) {
    acc0 = acc1 = acc2 = acc3 = (f32x4){0.f, 0.f, 0.f, 0.f};
#pragma unroll
    for (int ks = 0; ks < 16; ks++) {
      bf16x8 a = *(const bf16x8*)(hA + (((size_t)ks * 4 + quad) * 16 + ln15) * 8);
      bf16x8 b0v, b1v, b2v, b3v;
      if (ks < 12) {
        b0v = bf[0][ks]; b1v = bf[1][ks]; b2v = bf[2][ks]; b3v = bf[3][ks];
      } else if (ks == 12) {
        b0v = *(const bf16x8*)(bl + (((size_t)wave * 4 + 0) * 64 + lane) * 8);
        b1v = *(const bf16x8*)(bl + (((size_t)wave * 4 + 1) * 64 + lane) * 8);
        b2v = *(const bf16x8*)(bl + (((size_t)wave * 4 + 2) * 64 + lane) * 8);
        b3v = *(const bf16x8*)(bl + (((size_t)wave * 4 + 3) * 64 + lane) * 8);
      } else {
        b0v = *(const bf16x8*)(rpack + (((size_t)(nt0 + 0) * 16 + ks) * 64 + lane) * 8);
        b1v = *(const bf16x8*)(rpack + (((size_t)(nt0 + 1) * 16 + ks) * 64 + lane) * 8);
        b2v = *(const bf16x8*)(rpack + (((size_t)(nt0 + 2) * 16 + ks) * 64 + lane) * 8);
        b3v = *(const bf16x8*)(rpack + (((size_t)(nt0 + 3) * 16 + ks) * 64 + lane) * 8);
      }
      acc0 = __builtin_amdgcn_mfma_f32_16x16x32_bf16(a, b0v, acc0, 0, 0, 0);
      acc1 = __builtin_amdgcn_mfma_f32_16x16x32_bf16(a, b1v, acc1, 0, 0, 0);
      acc2 = __builtin_amdgcn_mfma_f32_16x16x32_bf16(a, b2v, acc2, 0, 0, 0);
      acc3 = __builtin_amdgcn_mfma_f32_16x16x32_bf16(a, b3v, acc3, 0, 0, 0);
    }

    // xk tiles for this step, C-fragment order: one dwordx2 per n-tile
    const uint16_t* xb = xkp + (((size_t)t * 64 + g) * 32) * 256;
    u16x4 xv0 = *(const u16x4*)(xb + ((size_t)(nt0 + 0)) * 256 + (size_t)lane * 4);
    u16x4 xv1 = *(const u16x4*)(xb + ((size_t)(nt0 + 1)) * 256 + (size_t)lane * 4);
    u16x4 xv2 = *(const u16x4*)(xb + ((size_t)(nt0 + 2)) * 256 + (size_t)lane * 4);
    u16x4 xv3 = *(const u16x4*)(xb + ((size_t)(nt0 + 3)) * 256 + (size_t)lane * 4);

    uint16_t hv[4][4];
#pragma unroll
    for (int r = 0; r < 4; r++) {
      hv[0][r] = f2bf(tanh_fast(acc0[r] + bf2f(xv0[r])));
      hv[1][r] = f2bf(tanh_fast(acc1[r] + bf2f(xv1[r])));
      hv[2][r] = f2bf(tanh_fast(acc2[r] + bf2f(xv2[r])));
      hv[3][r] = f2bf(tanh_fast(acc3[r] + bf2f(xv3[r])));
    }

    __syncthreads();  // all A-reads of step t complete
#pragma unroll
    for (int nt = 0; nt < 4; nt++) {
      int col = (nt0 + nt) * 16 + ln15;
      int chunk = col >> 3, j = col & 7;
#pragma unroll
      for (int r = 0; r < 4; r++) {
        int row = quad * 4 + r;
        hA[((size_t)chunk * 16 + row) * 8 + j] = hv[nt][r];
      }
    }
    __syncthreads();  // h(t+1) visible to all waves
  }

  // final FC + sigmoid: wave w handles rows 2w, 2w+1 of this block
#pragma unroll
  for (int rr = 0; rr < 2; rr++) {
    int row = wave * 2 + rr;
    const uint16_t* hr = hA + ((size_t)lane * 16 + row) * 8;  // chunk=lane, j=0..7
    float p = 0.f;
#pragma unroll
    for (int j = 0; j < 8; j++) p += bf2f(hr[j]) * fcw[lane * 8 + j];
#pragma unroll
    for (int off = 32; off; off >>= 1) p += __shfl_down(p, off);
    if (lane == 0) {
      float logit = p + fcb[0];
      out[g * 16 + row] = 1.0f / (1.0f + __expf(-logit));
    }
  }
}

// ---------------- launcher ----------------
extern "C" void kernel_launch(void* const* d_in, const int* in_sizes, int n_in,
                              void* d_out, int out_size, void* d_ws, size_t ws_size,
                              hipStream_t stream) {
  const int* tokens   = (const int*)d_in[0];
  const float* emb    = (const float*)d_in[1];
  const float* kernel_w = (const float*)d_in[2];
  const float* rec_w  = (const float*)d_in[3];
  const float* bias   = (const float*)d_in[4];
  const float* fcw    = (const float*)d_in[5];
  const float* fcb    = (const float*)d_in[6];
  float* out = (float*)d_out;

  // workspace layout: emb_bf16 51.2MB | kpack 0.5MB | rpack 0.5MB | xkp 83.9MB
  uint16_t* embb  = (uint16_t*)d_ws;
  uint16_t* kpack = embb + (size_t)NV * NE;
  uint16_t* rpack = kpack + (size_t)NE * NU;
  uint16_t* xkp   = rpack + (size_t)NU * NU;

  hipLaunchKernelGGL(emb_to_bf16, dim3(25000), dim3(256), 0, stream, emb, embb);
  hipLaunchKernelGGL(pack_w, dim3(128), dim3(256), 0, stream, kernel_w, kpack);
  hipLaunchKernelGGL(pack_w, dim3(128), dim3(256), 0, stream, rec_w, rpack);
  hipLaunchKernelGGL(proj_gemm, dim3(1280), dim3(256), 0, stream, tokens, embb, kpack, bias, xkp);
  hipLaunchKernelGGL(rnn_rec, dim3(64), dim3(512), 0, stream, xkp, rpack, fcw, fcb, out);
}

// Round 3
// 560.653 us; speedup vs baseline: 2.6349x; 1.1876x over previous
//
#include <hip/hip_runtime.h>
#include <stdint.h>

// Problem constants (B, T, V, E, U)
constexpr int NB = 1024;
constexpr int NT = 80;
constexpr int NV = 50000;
constexpr int NE = 512;
constexpr int NU = 512;

typedef __attribute__((ext_vector_type(8))) __bf16 bf16x8;
typedef __attribute__((ext_vector_type(4))) float f32x4;
typedef __attribute__((ext_vector_type(4))) uint16_t u16x4;
typedef __attribute__((ext_vector_type(4))) float float4v;
typedef __attribute__((ext_vector_type(4))) uint32_t u32x4;

__device__ __forceinline__ uint16_t f2bf(float f) {
  uint32_t u = __builtin_bit_cast(uint32_t, f);
  u += 0x7FFFu + ((u >> 16) & 1u);   // round-to-nearest-even
  return (uint16_t)(u >> 16);
}
__device__ __forceinline__ float bf2f(uint16_t h) {
  uint32_t u = ((uint32_t)h) << 16;
  return __builtin_bit_cast(float, u);
}
__device__ __forceinline__ float tanh_fast(float x) {
  float e = __expf(2.0f * x);
  return 1.0f - 2.0f / (e + 1.0f);
}

// ---------------- prep kernels ----------------

__global__ __launch_bounds__(256) void emb_to_bf16(const float* __restrict__ in,
                                                   uint16_t* __restrict__ out) {
  int i = blockIdx.x * 256 + threadIdx.x;           // 6,400,000 float4s
  float4v v = ((const float4v*)in)[i];
  u16x4 o;
  o.x = f2bf(v.x); o.y = f2bf(v.y); o.z = f2bf(v.z); o.w = f2bf(v.w);
  ((u16x4*)out)[i] = o;
}

// Pack a [K=512][N=512] fp32 weight into MFMA-B-fragment order:
// pack[nt][ks][lane][j] = bf16( W[ks*32 + (lane>>4)*8 + j][nt*16 + (lane&15)] )
__global__ __launch_bounds__(256) void pack_w(const float* __restrict__ w,
                                              uint16_t* __restrict__ out) {
  int idx = blockIdx.x * 256 + threadIdx.x;  // 0..32767 = 32 nt * 16 ks * 64 lanes
  int lane = idx & 63;
  int ks = (idx >> 6) & 15;
  int nt = idx >> 10;
  int n  = nt * 16 + (lane & 15);
  int k0 = ks * 32 + (lane >> 4) * 8;
  uint16_t v[8];
#pragma unroll
  for (int j = 0; j < 8; j++) v[j] = f2bf(w[(size_t)(k0 + j) * NU + n]);
  u16x4* o = (u16x4*)(out + (size_t)idx * 8);
  o[0] = (u16x4){v[0], v[1], v[2], v[3]};
  o[1] = (u16x4){v[4], v[5], v[6], v[7]};
}

// ---------------- projection GEMM ----------------
// Row order t-major: flat row gm = t*NB + b; block = 64 rows of one t.
// Output tiles in MFMA C-fragment order (tile = 256 u16, elem at lane*4+r).
// Depth-2 software pipeline on the A-gather to hide L3 latency.
__global__ __launch_bounds__(256, 2) void proj_gemm(const int* __restrict__ tokens,
                                                    const uint16_t* __restrict__ embb,
                                                    const uint16_t* __restrict__ kpack,
                                                    const float* __restrict__ bias,
                                                    uint16_t* __restrict__ xkp) {
  int wave = threadIdx.x >> 6;
  int lane = threadIdx.x & 63;
  int ln15 = lane & 15;
  int quad = lane >> 4;
  int m0 = blockIdx.x * 64;      // 1280 blocks: 80 t x 16 b-groups
  int t = m0 >> 10;
  int b0 = m0 & 1023;

  int tok[4];
#pragma unroll
  for (int mt = 0; mt < 4; mt++)
    tok[mt] = tokens[(size_t)(b0 + mt * 16 + ln15) * NT + t];

  float bv[8];
#pragma unroll
  for (int nt = 0; nt < 8; nt++) bv[nt] = bias[wave * 128 + nt * 16 + ln15];

  f32x4 acc[4][8];
#pragma unroll
  for (int mt = 0; mt < 4; mt++)
#pragma unroll
    for (int nt = 0; nt < 8; nt++) acc[mt][nt] = (f32x4){0.f, 0.f, 0.f, 0.f};

  bf16x8 aC[4], aN[4];
#pragma unroll
  for (int mt = 0; mt < 4; mt++) {
    aC[mt] = *(const bf16x8*)(embb + (size_t)tok[mt] * NE + 0 * 32 + quad * 8);
    aN[mt] = *(const bf16x8*)(embb + (size_t)tok[mt] * NE + 1 * 32 + quad * 8);
  }

#pragma unroll 1
  for (int ks = 0; ks < 16; ks++) {
    bf16x8 aF[4];
    int ksn = (ks + 2) & 15;   // wraps harmlessly for ks=14,15
#pragma unroll
    for (int mt = 0; mt < 4; mt++)
      aF[mt] = *(const bf16x8*)(embb + (size_t)tok[mt] * NE + ksn * 32 + quad * 8);
#pragma unroll
    for (int nt = 0; nt < 8; nt++) {
      int ntg = wave * 8 + nt;
      bf16x8 bfr = *(const bf16x8*)(kpack + (((size_t)ntg * 16 + ks) * 64 + lane) * 8);
#pragma unroll
      for (int mt = 0; mt < 4; mt++)
        acc[mt][nt] = __builtin_amdgcn_mfma_f32_16x16x32_bf16(aC[mt], bfr, acc[mt][nt], 0, 0, 0);
    }
#pragma unroll
    for (int mt = 0; mt < 4; mt++) { aC[mt] = aN[mt]; aN[mt] = aF[mt]; }
  }

  // epilogue: C-fragment-order tiles, coalesced 8B/lane stores
#pragma unroll
  for (int mt = 0; mt < 4; mt++) {
    int g = (b0 >> 4) + mt;
#pragma unroll
    for (int nt = 0; nt < 8; nt++) {
      int ntg = wave * 8 + nt;
      size_t tile = ((size_t)t * 64 + g) * 32 + ntg;
      u16x4 o;
      o.x = f2bf(acc[mt][nt][0] + bv[nt]);
      o.y = f2bf(acc[mt][nt][1] + bv[nt]);
      o.z = f2bf(acc[mt][nt][2] + bv[nt]);
      o.w = f2bf(acc[mt][nt][3] + bv[nt]);
      *(u16x4*)(xkp + tile * 256 + (size_t)lane * 4) = o;
    }
  }
}

// ---------------- recurrence ----------------
// 64 blocks x 512 threads. Block g owns rows g*16..+15, all 512 cols.
// Wave w owns n-tiles w*4..+3. R tiering: ks0..11 VGPR-resident (192 regs,
// pinned by waves_per_eu(2,2) -> 256-reg budget), ks12 in LDS, ks13..15
// streamed from L2 per step (issued at step top, consumed last).
// hA double-buffered (2x16KB) -> ONE raw s_barrier per step, lgkmcnt-only
// drain so global prefetches stay in flight. Total LDS = 64 KB.
__global__ void __attribute__((amdgpu_flat_work_group_size(512, 512)))
__attribute__((amdgpu_waves_per_eu(2, 2)))
rnn_rec(const uint16_t* __restrict__ xkp,
        const uint16_t* __restrict__ rpack,
        const float* __restrict__ fcw,
        const float* __restrict__ fcb,
        float* __restrict__ out) {
  __shared__ uint16_t hA[2][64 * 16 * 8];     // 2 x 16 KB: [buf][chunk][row][8]
  __shared__ uint16_t blB[8 * 4 * 64 * 8];    // 32 KB: ks==12 frags [wave][nt][lane][8]

  int g = blockIdx.x;
  int wave = threadIdx.x >> 6;
  int lane = threadIdx.x & 63;
  int ln15 = lane & 15;
  int quad = lane >> 4;
  int nt0 = wave * 4;

  // resident B-frags ks0..11 (192 VGPR)
  bf16x8 bf[4][12];
#pragma unroll
  for (int nt = 0; nt < 4; nt++)
#pragma unroll
    for (int ks = 0; ks < 12; ks++)
      bf[nt][ks] = *(const bf16x8*)(rpack + (((size_t)(nt0 + nt) * 16 + ks) * 64 + lane) * 8);

  // ks==12 slice into LDS
#pragma unroll
  for (int nt = 0; nt < 4; nt++)
    *(u32x4*)(blB + (((size_t)wave * 4 + nt) * 64 + lane) * 8) =
        *(const u32x4*)(rpack + (((size_t)(nt0 + nt) * 16 + 12) * 64 + lane) * 8);

  // zero h0 in buffer 0
  {
    u32x4 z = (u32x4){0u, 0u, 0u, 0u};
    ((u32x4*)hA[0])[threadIdx.x * 2] = z;
    ((u32x4*)hA[0])[threadIdx.x * 2 + 1] = z;
  }
  __syncthreads();

  for (int t = 0; t < NT; t++) {
    const uint16_t* hc = hA[t & 1];
    uint16_t* hn = hA[(t + 1) & 1];

    // xk tiles for this step (consumed after MFMA -> latency hidden)
    const uint16_t* xb = xkp + (((size_t)t * 64 + g) * 32) * 256;
    u16x4 xv[4];
#pragma unroll
    for (int nt = 0; nt < 4; nt++)
      xv[nt] = *(const u16x4*)(xb + ((size_t)(nt0 + nt)) * 256 + (size_t)lane * 4);

    // G1 stream: ks13,14 B-frags (issued now, consumed after the 12 reg slices)
    bf16x8 g13[4], g14[4];
#pragma unroll
    for (int nt = 0; nt < 4; nt++) {
      g13[nt] = *(const bf16x8*)(rpack + (((size_t)(nt0 + nt) * 16 + 13) * 64 + lane) * 8);
      g14[nt] = *(const bf16x8*)(rpack + (((size_t)(nt0 + nt) * 16 + 14) * 64 + lane) * 8);
    }

    f32x4 acc[4];
#pragma unroll
    for (int nt = 0; nt < 4; nt++) acc[nt] = (f32x4){0.f, 0.f, 0.f, 0.f};

    // ks0..11 from registers
#pragma unroll
    for (int ks = 0; ks < 12; ks++) {
      bf16x8 a = *(const bf16x8*)(hc + (((size_t)ks * 4 + quad) * 16 + ln15) * 8);
#pragma unroll
      for (int nt = 0; nt < 4; nt++)
        acc[nt] = __builtin_amdgcn_mfma_f32_16x16x32_bf16(a, bf[nt][ks], acc[nt], 0, 0, 0);
    }
    // ks12 from LDS
    {
      bf16x8 a = *(const bf16x8*)(hc + (((size_t)12 * 4 + quad) * 16 + ln15) * 8);
#pragma unroll
      for (int nt = 0; nt < 4; nt++) {
        bf16x8 b = *(const bf16x8*)(blB + (((size_t)wave * 4 + nt) * 64 + lane) * 8);
        acc[nt] = __builtin_amdgcn_mfma_f32_16x16x32_bf16(a, b, acc[nt], 0, 0, 0);
      }
    }
    // ks13,14 streamed (G1)
    {
      bf16x8 a = *(const bf16x8*)(hc + (((size_t)13 * 4 + quad) * 16 + ln15) * 8);
#pragma unroll
      for (int nt = 0; nt < 4; nt++)
        acc[nt] = __builtin_amdgcn_mfma_f32_16x16x32_bf16(a, g13[nt], acc[nt], 0, 0, 0);
    }
    {
      bf16x8 a = *(const bf16x8*)(hc + (((size_t)14 * 4 + quad) * 16 + ln15) * 8);
#pragma unroll
      for (int nt = 0; nt < 4; nt++)
        acc[nt] = __builtin_amdgcn_mfma_f32_16x16x32_bf16(a, g14[nt], acc[nt], 0, 0, 0);
    }
    // G2 stream: ks15 (issued here; short exposure covered by co-resident wave)
    {
      bf16x8 g15[4];
#pragma unroll
      for (int nt = 0; nt < 4; nt++)
        g15[nt] = *(const bf16x8*)(rpack + (((size_t)(nt0 + nt) * 16 + 15) * 64 + lane) * 8);
      bf16x8 a = *(const bf16x8*)(hc + (((size_t)15 * 4 + quad) * 16 + ln15) * 8);
#pragma unroll
      for (int nt = 0; nt < 4; nt++)
        acc[nt] = __builtin_amdgcn_mfma_f32_16x16x32_bf16(a, g15[nt], acc[nt], 0, 0, 0);
    }

    // tanh + write h(t+1) into the other buffer (no barrier needed before writes)
#pragma unroll
    for (int nt = 0; nt < 4; nt++) {
      int cb = (nt0 + nt) * 2 + (ln15 >> 3);   // chunk index of this col
      int j = ln15 & 7;
#pragma unroll
      for (int r = 0; r < 4; r++) {
        float h = tanh_fast(acc[nt][r] + bf2f(xv[nt][r]));
        hn[((size_t)cb * 16 + quad * 4 + r) * 8 + j] = f2bf(h);
      }
    }

    // LDS-only drain + raw barrier: vmcnt loads stay in flight
    asm volatile("s_waitcnt lgkmcnt(0)\n\ts_barrier" ::: "memory");
  }

  // final FC + sigmoid: wave w handles rows 2w, 2w+1 (h_final in buffer 0)
#pragma unroll
  for (int rr = 0; rr < 2; rr++) {
    int row = wave * 2 + rr;
    const uint16_t* hr = hA[0] + ((size_t)lane * 16 + row) * 8;  // chunk=lane
    float p = 0.f;
#pragma unroll
    for (int j = 0; j < 8; j++) p += bf2f(hr[j]) * fcw[lane * 8 + j];
#pragma unroll
    for (int off = 32; off; off >>= 1) p += __shfl_down(p, off);
    if (lane == 0) {
      float logit = p + fcb[0];
      out[g * 16 + row] = 1.0f / (1.0f + __expf(-logit));
    }
  }
}

// ---------------- launcher ----------------
extern "C" void kernel_launch(void* const* d_in, const int* in_sizes, int n_in,
                              void* d_out, int out_size, void* d_ws, size_t ws_size,
                              hipStream_t stream) {
  const int* tokens   = (const int*)d_in[0];
  const float* emb    = (const float*)d_in[1];
  const float* kernel_w = (const float*)d_in[2];
  const float* rec_w  = (const float*)d_in[3];
  const float* bias   = (const float*)d_in[4];
  const float* fcw    = (const float*)d_in[5];
  const float* fcb    = (const float*)d_in[6];
  float* out = (float*)d_out;

  // workspace: emb_bf16 51.2MB | kpack 0.5MB | rpack 0.5MB | xkp 83.9MB
  uint16_t* embb  = (uint16_t*)d_ws;
  uint16_t* kpack = embb + (size_t)NV * NE;
  uint16_t* rpack = kpack + (size_t)NE * NU;
  uint16_t* xkp   = rpack + (size_t)NU * NU;

  hipLaunchKernelGGL(emb_to_bf16, dim3(25000), dim3(256), 0, stream, emb, embb);
  hipLaunchKernelGGL(pack_w, dim3(128), dim3(256), 0, stream, kernel_w, kpack);
  hipLaunchKernelGGL(pack_w, dim3(128), dim3(256), 0, stream, rec_w, rpack);
  hipLaunchKernelGGL(proj_gemm, dim3(1280), dim3(256), 0, stream, tokens, embb, kpack, bias, xkp);
  hipLaunchKernelGGL(rnn_rec, dim3(64), dim3(512), 0, stream, xkp, rpack, fcw, fcb, out);
}